// Round 1
// baseline (2451.420 us; speedup 1.0000x reference)
//
#include <hip/hip_runtime.h>

#define TT 512
#define BB 1024

__device__ __forceinline__ float frcp(float x){ return __builtin_amdgcn_rcpf(x); }
__device__ __forceinline__ float fexp2(float x){ return __builtin_amdgcn_exp2f(x); }
// cos(x), x in radians: exact fract range-reduction then V_COS (takes revolutions)
__device__ __forceinline__ float fcosr(float x){
  float r = x * 0.15915494309189535f;
  r = r - floorf(r);
  return __builtin_amdgcn_cosf(r);
}
__device__ __forceinline__ float fsig(float x){
  return frcp(1.0f + fexp2(-1.4426950408889634f * x));
}
__device__ __forceinline__ float ftanh(float x){
  // 1 - 2/(exp(2x)+1); safe at both saturations
  return 1.0f - 2.0f * frcp(fexp2(2.8853900817779268f * x) + 1.0f);
}

// Phase 1: xpre[t][c][b] for c in [0,40): c<32 -> gate g=c>>3, j=c&7:
//   x@Wg[:64] + bg + thg ; c>=32 -> x@Wi2k + bi2k - bh2k  (ky' with bh2k folded)
// Layout: buf as float4: buf4[(t*10+q)*BB + b], component cc -> c = q*4+cc
__global__ __launch_bounds__(256) void qlstm_proj(
    const float* __restrict__ x,   // [tc, BB, 64] (chunk offset applied by host)
    const float* __restrict__ Wf, const float* __restrict__ bf, const float* __restrict__ thf,
    const float* __restrict__ Wi, const float* __restrict__ bi, const float* __restrict__ thi,
    const float* __restrict__ Wu, const float* __restrict__ bu, const float* __restrict__ thu,
    const float* __restrict__ Wo, const float* __restrict__ bo, const float* __restrict__ tho,
    const float* __restrict__ bh2k,
    const float* __restrict__ Wi2k, const float* __restrict__ bi2k,
    float* __restrict__ buf)
{
  __shared__ float4 wl4[64][10];
  __shared__ float bias[40];
  int tid = threadIdx.x;
  float* wl = (float*)wl4;
  for (int idx = tid; idx < 64*40; idx += 256){
    int d = idx / 40, c = idx - d*40;
    float v;
    if (c < 32){
      int g = c >> 3, j = c & 7;
      const float* W = (g==0)?Wf:((g==1)?Wi:((g==2)?Wu:Wo));
      v = W[d*8+j];
    } else {
      v = Wi2k[d*8 + (c-32)];
    }
    wl[d*40+c] = v;
  }
  if (tid < 40){
    int c = tid; float v;
    if (c < 32){
      int g = c >> 3, j = c & 7;
      const float* bp = (g==0)?bf:((g==1)?bi:((g==2)?bu:bo));
      const float* tp = (g==0)?thf:((g==1)?thi:((g==2)?thu:tho));
      v = bp[j] + tp[j];
    } else {
      v = bi2k[c-32] - bh2k[c-32];
    }
    bias[c] = v;
  }
  __syncthreads();

  // 2 rows (t,b pairs) per thread; block covers 512 consecutive rows
  long r0 = (long)blockIdx.x*512 + tid;
  long r1 = r0 + 256;
  const float4* x0 = (const float4*)(x + r0*64);
  const float4* x1 = (const float4*)(x + r1*64);
  float4 a0[10], a1[10];
#pragma unroll
  for (int q=0;q<10;++q){
    a0[q] = make_float4(bias[q*4+0],bias[q*4+1],bias[q*4+2],bias[q*4+3]);
    a1[q] = a0[q];
  }
#pragma unroll 1
  for (int d4=0; d4<16; ++d4){
    float4 xv0 = x0[d4];
    float4 xv1 = x1[d4];
#pragma unroll
    for (int dd=0; dd<4; ++dd){
      float s0 = (dd==0)?xv0.x:((dd==1)?xv0.y:((dd==2)?xv0.z:xv0.w));
      float s1 = (dd==0)?xv1.x:((dd==1)?xv1.y:((dd==2)?xv1.z:xv1.w));
#pragma unroll
      for (int q=0;q<10;++q){
        float4 wv = wl4[d4*4+dd][q];
        a0[q].x += s0*wv.x; a0[q].y += s0*wv.y; a0[q].z += s0*wv.z; a0[q].w += s0*wv.w;
        a1[q].x += s1*wv.x; a1[q].y += s1*wv.y; a1[q].z += s1*wv.z; a1[q].w += s1*wv.w;
      }
    }
  }
  int t0_ = (int)(r0 >> 10), b0 = (int)(r0 & 1023);
  int t1_ = (int)(r1 >> 10), b1 = (int)(r1 & 1023);
  float4* ob = (float4*)buf;
#pragma unroll
  for (int q=0;q<10;++q){
    ob[(t0_*10 + q)*BB + b0] = a0[q];
    ob[(t1_*10 + q)*BB + b1] = a1[q];
  }
}

// Phase 2: sequential scan. One thread per batch element; recurrent weights
// (rows 64..71 of each gate W, plus Wh2k) broadcast from LDS.
__global__ __launch_bounds__(64) void qlstm_scan(
    const float* __restrict__ buf,
    const float* __restrict__ Wf, const float* __restrict__ Wi,
    const float* __restrict__ Wu, const float* __restrict__ Wo,
    const float* __restrict__ Wh2k,
    float* __restrict__ out,
    float* __restrict__ hstate, float* __restrict__ cstate,
    int t0, int tc, int initf, int lastf)
{
  __shared__ float4 wl[5][8][2];  // [g][k][j4]; g=4 is Wh2k
  int tid = threadIdx.x;
  for (int idx = tid; idx < 320; idx += 64){
    int g = idx >> 6, rem = idx & 63, k = rem >> 3, j = rem & 7;
    const float* W = (g==0)?(Wf+512):((g==1)?(Wi+512):((g==2)?(Wu+512):((g==3)?(Wo+512):Wh2k)));
    ((float*)&wl[g][k][0])[j] = W[k*8+j];
  }
  __syncthreads();

  int b = blockIdx.x*64 + tid;
  float h[8], c[8];
  if (initf){
#pragma unroll
    for (int j=0;j<8;++j){ h[j]=0.f; c[j]=0.f; }
  } else {
    float4 a = *(const float4*)&hstate[b*8];
    float4 d = *(const float4*)&hstate[b*8+4];
    float4 e = *(const float4*)&cstate[b*8];
    float4 f = *(const float4*)&cstate[b*8+4];
    h[0]=a.x;h[1]=a.y;h[2]=a.z;h[3]=a.w; h[4]=d.x;h[5]=d.y;h[6]=d.z;h[7]=d.w;
    c[0]=e.x;c[1]=e.y;c[2]=e.z;c[3]=e.w; c[4]=f.x;c[5]=f.y;c[6]=f.z;c[7]=f.w;
  }
  const float4* bq = (const float4*)buf;
#pragma unroll 1
  for (int tt=0; tt<tc; ++tt){
    // xpre loads issued first; first use is after the matvec -> latency hidden
    float xc[40];
#pragma unroll
    for (int q=0;q<10;++q){
      float4 v = bq[(tt*10+q)*BB + b];
      xc[q*4+0]=v.x; xc[q*4+1]=v.y; xc[q*4+2]=v.z; xc[q*4+3]=v.w;
    }
    float acc[5][8];
#pragma unroll
    for (int g=0;g<5;++g)
#pragma unroll
      for (int j=0;j<8;++j) acc[g][j]=0.f;
#pragma unroll
    for (int k=0;k<8;++k){
      float hv = h[k];
#pragma unroll
      for (int g=0;g<5;++g){
        float4 w0 = wl[g][k][0], w1 = wl[g][k][1];
        acc[g][0] += hv*w0.x; acc[g][1] += hv*w0.y;
        acc[g][2] += hv*w0.z; acc[g][3] += hv*w0.w;
        acc[g][4] += hv*w1.x; acc[g][5] += hv*w1.y;
        acc[g][6] += hv*w1.z; acc[g][7] += hv*w1.w;
      }
    }
    // kernel weight w = |prod cos(0.5*(kx - ky))|
    float p = 1.f;
#pragma unroll
    for (int j=0;j<8;++j) p *= fcosr(0.5f*(acc[4][j] - xc[32+j]));
    float wk = fabsf(p);
    // gates: qlayer then scale by wk
    float gq[4][8];
#pragma unroll
    for (int g=0; g<4; ++g){
      float z[8];
#pragma unroll
      for (int j=0;j<8;++j) z[j] = fcosr(acc[g][j] + xc[g*8+j]);
      gq[g][0] = ((z[1]*z[2])*(z[3]*z[4]))*((z[5]*z[6])*z[7]);  // prod z[1:]
      float cp = z[0];
#pragma unroll
      for (int j=1;j<8;++j){ cp *= z[j]; gq[g][j] = cp; }       // cumprod
#pragma unroll
      for (int j=0;j<8;++j) gq[g][j] *= wk;
    }
#pragma unroll
    for (int j=0;j<8;++j){
      float fg = fsig(gq[0][j]);
      float ig = fsig(gq[1][j]);
      float ug = ftanh(gq[2][j]);
      float og = fsig(gq[3][j]);
      c[j] = fg*c[j] + ig*ug;
      h[j] = og*ftanh(c[j]);
    }
    int t = t0 + tt;
    float4* op = (float4*)(out + ((size_t)t*BB + b)*8);
    op[0] = make_float4(h[0],h[1],h[2],h[3]);
    op[1] = make_float4(h[4],h[5],h[6],h[7]);
  }
  if (lastf){
    float* hx = out + (size_t)TT*BB*8 + (size_t)b*8;
    float* cx = out + (size_t)TT*BB*8 + (size_t)BB*8 + (size_t)b*8;
    *(float4*)hx     = make_float4(h[0],h[1],h[2],h[3]);
    *(float4*)(hx+4) = make_float4(h[4],h[5],h[6],h[7]);
    *(float4*)cx     = make_float4(c[0],c[1],c[2],c[3]);
    *(float4*)(cx+4) = make_float4(c[4],c[5],c[6],c[7]);
  } else {
    *(float4*)&hstate[b*8]   = make_float4(h[0],h[1],h[2],h[3]);
    *(float4*)&hstate[b*8+4] = make_float4(h[4],h[5],h[6],h[7]);
    *(float4*)&cstate[b*8]   = make_float4(c[0],c[1],c[2],c[3]);
    *(float4*)&cstate[b*8+4] = make_float4(c[4],c[5],c[6],c[7]);
  }
}

extern "C" void kernel_launch(void* const* d_in, const int* in_sizes, int n_in,
                              void* d_out, int out_size, void* d_ws, size_t ws_size,
                              hipStream_t stream)
{
  const float* x    = (const float*)d_in[0];
  const float* Wf   = (const float*)d_in[1];
  const float* bf   = (const float*)d_in[2];
  const float* thf  = (const float*)d_in[3];
  const float* Wi   = (const float*)d_in[4];
  const float* bi   = (const float*)d_in[5];
  const float* thi  = (const float*)d_in[6];
  const float* Wu   = (const float*)d_in[7];
  const float* bu   = (const float*)d_in[8];
  const float* thu  = (const float*)d_in[9];
  const float* Wo   = (const float*)d_in[10];
  const float* bo   = (const float*)d_in[11];
  const float* tho  = (const float*)d_in[12];
  const float* Wh2k = (const float*)d_in[13];
  const float* bh2k = (const float*)d_in[14];
  const float* Wi2k = (const float*)d_in[15];
  const float* bi2k = (const float*)d_in[16];
  float* out = (float*)d_out;

  // ws layout: hstate[8192 f] | cstate[8192 f] | xpre buf
  float* hstate = (float*)d_ws;
  float* cstate = hstate + BB*8;
  float* buf    = cstate + BB*8;
  long long avail = (long long)ws_size - (long long)(2*BB*8*sizeof(float));
  const long long per_step = 40ll*BB*sizeof(float);  // 160 KiB per time step
  int tc = TT;
  while (tc > 1 && (long long)tc*per_step > avail) tc >>= 1;

  for (int t0 = 0; t0 < TT; t0 += tc){
    int cur = (TT - t0 < tc) ? (TT - t0) : tc;
    qlstm_proj<<<(cur*BB)/512, 256, 0, stream>>>(
        x + (size_t)t0*BB*64,
        Wf,bf,thf, Wi,bi,thi, Wu,bu,thu, Wo,bo,tho,
        bh2k, Wi2k, bi2k, buf);
    qlstm_scan<<<BB/64, 64, 0, stream>>>(
        buf, Wf, Wi, Wu, Wo, Wh2k, out, hstate, cstate,
        t0, cur, (t0==0)?1:0, (t0+cur>=TT)?1:0);
  }
}

// Round 2
// 512.940 us; speedup vs baseline: 4.7792x; 4.7792x over previous
//
#include <hip/hip_runtime.h>

#define TT 512
#define BB 1024

__device__ __forceinline__ float frcp(float x){ return __builtin_amdgcn_rcpf(x); }
__device__ __forceinline__ float fexp2(float x){ return __builtin_amdgcn_exp2f(x); }
// cos(x), x in radians: exact fract range-reduction then V_COS (takes revolutions)
__device__ __forceinline__ float fcosr(float x){
  float r = x * 0.15915494309189535f;
  r = r - floorf(r);
  return __builtin_amdgcn_cosf(r);
}
__device__ __forceinline__ float fsig(float x){
  return frcp(1.0f + fexp2(-1.4426950408889634f * x));
}
__device__ __forceinline__ float ftanh(float x){
  return 1.0f - 2.0f * frcp(fexp2(2.8853900817779268f * x) + 1.0f);
}

// float-through-int DPP / swizzle helpers
#define UDPP(v, ctrl) __int_as_float(__builtin_amdgcn_update_dpp(0, __float_as_int(v), (ctrl), 0xF, 0xF, true))
#define SWZ(v, imm)   __int_as_float(__builtin_amdgcn_ds_swizzle(__float_as_int(v), (imm)))

// Phase 1: xpre[t][b][c] for c in [0,40): c<32 -> gate g=c>>3, jj=c&7:
//   x@Wg[:64] + bg + thg ; c>=32 -> x@Wi2k + bi2k - bh2k  (ky' with bh2k folded)
__global__ __launch_bounds__(256) void qlstm_proj(
    const float* __restrict__ x,   // [tc, BB, 64] (chunk offset applied by host)
    const float* __restrict__ Wf, const float* __restrict__ bf, const float* __restrict__ thf,
    const float* __restrict__ Wi, const float* __restrict__ bi, const float* __restrict__ thi,
    const float* __restrict__ Wu, const float* __restrict__ bu, const float* __restrict__ thu,
    const float* __restrict__ Wo, const float* __restrict__ bo, const float* __restrict__ tho,
    const float* __restrict__ bh2k,
    const float* __restrict__ Wi2k, const float* __restrict__ bi2k,
    float* __restrict__ buf)
{
  __shared__ float4 wl4[64][10];
  __shared__ float bias[40];
  int tid = threadIdx.x;
  float* wl = (float*)wl4;
  for (int idx = tid; idx < 64*40; idx += 256){
    int d = idx / 40, c = idx - d*40;
    float v;
    if (c < 32){
      int g = c >> 3, jj = c & 7;
      const float* W = (g==0)?Wf:((g==1)?Wi:((g==2)?Wu:Wo));
      v = W[d*8+jj];
    } else {
      v = Wi2k[d*8 + (c-32)];
    }
    wl[d*40+c] = v;
  }
  if (tid < 40){
    int c = tid; float v;
    if (c < 32){
      int g = c >> 3, jj = c & 7;
      const float* bp = (g==0)?bf:((g==1)?bi:((g==2)?bu:bo));
      const float* tp = (g==0)?thf:((g==1)?thi:((g==2)?thu:tho));
      v = bp[jj] + tp[jj];
    } else {
      v = bi2k[c-32] - bh2k[c-32];
    }
    bias[c] = v;
  }
  __syncthreads();

  long r0 = (long)blockIdx.x*512 + tid;
  long r1 = r0 + 256;
  const float4* x0 = (const float4*)(x + r0*64);
  const float4* x1 = (const float4*)(x + r1*64);
  float4 a0[10], a1[10];
#pragma unroll
  for (int q=0;q<10;++q){
    a0[q] = make_float4(bias[q*4+0],bias[q*4+1],bias[q*4+2],bias[q*4+3]);
    a1[q] = a0[q];
  }
#pragma unroll 1
  for (int d4=0; d4<16; ++d4){
    float4 xv0 = x0[d4];
    float4 xv1 = x1[d4];
#pragma unroll
    for (int dd=0; dd<4; ++dd){
      float s0 = (dd==0)?xv0.x:((dd==1)?xv0.y:((dd==2)?xv0.z:xv0.w));
      float s1 = (dd==0)?xv1.x:((dd==1)?xv1.y:((dd==2)?xv1.z:xv1.w));
#pragma unroll
      for (int q=0;q<10;++q){
        float4 wv = wl4[d4*4+dd][q];
        a0[q].x += s0*wv.x; a0[q].y += s0*wv.y; a0[q].z += s0*wv.z; a0[q].w += s0*wv.w;
        a1[q].x += s1*wv.x; a1[q].y += s1*wv.y; a1[q].z += s1*wv.z; a1[q].w += s1*wv.w;
      }
    }
  }
  float4* ob0 = (float4*)(buf + (size_t)r0*40);
  float4* ob1 = (float4*)(buf + (size_t)r1*40);
#pragma unroll
  for (int q=0;q<10;++q){ ob0[q] = a0[q]; ob1[q] = a1[q]; }
}

// Phase 2: sequential scan. 8 lanes per batch element (lane j = hidden unit j).
// Recurrent weights live in 40 VGPRs/lane; h broadcast via ds_swizzle; cumprod
// via DPP row_shr; group products via quad_perm DPP + swizzle xor4.
__global__ __launch_bounds__(512) void qlstm_scan(
    const float* __restrict__ buf,
    const float* __restrict__ Wf, const float* __restrict__ Wi,
    const float* __restrict__ Wu, const float* __restrict__ Wo,
    const float* __restrict__ Wh2k,
    float* __restrict__ out,
    float* __restrict__ hstate, float* __restrict__ cstate,
    int t0, int tc, int initf, int lastf)
{
  int tid = threadIdx.x;
  int j = tid & 7;
  int b = blockIdx.x*64 + (tid >> 3);

  float wr[5][8];
#pragma unroll
  for (int k=0;k<8;++k){
    wr[0][k] = Wf[(64+k)*8 + j];
    wr[1][k] = Wi[(64+k)*8 + j];
    wr[2][k] = Wu[(64+k)*8 + j];
    wr[3][k] = Wo[(64+k)*8 + j];
    wr[4][k] = Wh2k[k*8 + j];
  }

  float h, c;
  if (initf){ h = 0.f; c = 0.f; }
  else { h = hstate[b*8+j]; c = cstate[b*8+j]; }

  const float* bp = buf + (size_t)b*40 + j;
  float xn0,xn1,xn2,xn3,xn4;
  { const float* p = bp;
    xn0=p[0]; xn1=p[8]; xn2=p[16]; xn3=p[24]; xn4=p[32]; }

#pragma unroll 1
  for (int tt=0; tt<tc; ++tt){
    float x0=xn0, x1=xn1, x2=xn2, x3=xn3, xk=xn4;
    if (tt+1 < tc){
      const float* p = bp + (size_t)(tt+1)*BB*40;
      xn0=p[0]; xn1=p[8]; xn2=p[16]; xn3=p[24]; xn4=p[32];
    }
    float a0=0.f,a1=0.f,a2=0.f,a3=0.f,a4=0.f;
#define STEPK(K) { \
    float hk = SWZ(h, ((K)<<5)|0x18); \
    a0 = fmaf(hk, wr[0][K], a0); a1 = fmaf(hk, wr[1][K], a1); \
    a2 = fmaf(hk, wr[2][K], a2); a3 = fmaf(hk, wr[3][K], a3); \
    a4 = fmaf(hk, wr[4][K], a4); }
    STEPK(0) STEPK(1) STEPK(2) STEPK(3) STEPK(4) STEPK(5) STEPK(6) STEPK(7)
#undef STEPK

    // kernel weight: |prod_j cos(0.5*(kx_j - ky_j))|, product over the 8-lane group
    float kv = fcosr(0.5f*(a4 - xk));
    kv *= UDPP(kv, 0xB1);      // quad_perm xor1
    kv *= UDPP(kv, 0x4E);      // quad_perm xor2
    kv *= SWZ(kv, 0x101F);     // xor4
    float wk = fabsf(kv);

    // per-gate qlayer: z = cos(acc + xc); out_0 = prod z[1:], out_j = cumprod z[0..j]
#define GATEQ(ZV, GQ) { \
    float zz = (ZV); \
    float pz = zz, s; \
    s = UDPP(pz, 0x111); pz = (j>=1)? pz*s : pz; \
    s = UDPP(pz, 0x112); pz = (j>=2)? pz*s : pz; \
    s = UDPP(pz, 0x114); pz = (j>=4)? pz*s : pz; \
    float q = (j==0)? 1.0f : zz; \
    q *= UDPP(q, 0xB1); \
    q *= UDPP(q, 0x4E); \
    q *= SWZ(q, 0x101F); \
    GQ = ((j==0)? q : pz) * wk; }

    float gf, gi, gu, go;
    GATEQ(fcosr(a0 + x0), gf)
    GATEQ(fcosr(a1 + x1), gi)
    GATEQ(fcosr(a2 + x2), gu)
    GATEQ(fcosr(a3 + x3), go)
#undef GATEQ

    float fg = fsig(gf);
    float ig = fsig(gi);
    float ug = ftanh(gu);
    float og = fsig(go);
    c = fg*c + ig*ug;
    h = og*ftanh(c);

    out[((size_t)(t0+tt)*BB + b)*8 + j] = h;
  }

  if (lastf){
    out[(size_t)TT*BB*8 + (size_t)b*8 + j] = h;
    out[(size_t)TT*BB*8 + (size_t)BB*8 + (size_t)b*8 + j] = c;
  } else {
    hstate[b*8+j] = h;
    cstate[b*8+j] = c;
  }
}

extern "C" void kernel_launch(void* const* d_in, const int* in_sizes, int n_in,
                              void* d_out, int out_size, void* d_ws, size_t ws_size,
                              hipStream_t stream)
{
  const float* x    = (const float*)d_in[0];
  const float* Wf   = (const float*)d_in[1];
  const float* bf   = (const float*)d_in[2];
  const float* thf  = (const float*)d_in[3];
  const float* Wi   = (const float*)d_in[4];
  const float* bi   = (const float*)d_in[5];
  const float* thi  = (const float*)d_in[6];
  const float* Wu   = (const float*)d_in[7];
  const float* bu   = (const float*)d_in[8];
  const float* thu  = (const float*)d_in[9];
  const float* Wo   = (const float*)d_in[10];
  const float* bo   = (const float*)d_in[11];
  const float* tho  = (const float*)d_in[12];
  const float* Wh2k = (const float*)d_in[13];
  const float* bh2k = (const float*)d_in[14];
  const float* Wi2k = (const float*)d_in[15];
  const float* bi2k = (const float*)d_in[16];
  float* out = (float*)d_out;

  // ws layout: hstate[8192 f] | cstate[8192 f] | xpre buf [tc][BB][40]
  float* hstate = (float*)d_ws;
  float* cstate = hstate + BB*8;
  float* buf    = cstate + BB*8;
  long long avail = (long long)ws_size - (long long)(2*BB*8*sizeof(float));
  const long long per_step = 40ll*BB*sizeof(float);  // 160 KiB per time step
  int tc = TT;
  while (tc > 1 && (long long)tc*per_step > avail) tc >>= 1;

  for (int t0 = 0; t0 < TT; t0 += tc){
    int cur = (TT - t0 < tc) ? (TT - t0) : tc;
    qlstm_proj<<<(cur*BB)/512, 256, 0, stream>>>(
        x + (size_t)t0*BB*64,
        Wf,bf,thf, Wi,bi,thi, Wu,bu,thu, Wo,bo,tho,
        bh2k, Wi2k, bi2k, buf);
    qlstm_scan<<<BB/64, 512, 0, stream>>>(
        buf, Wf, Wi, Wu, Wo, Wh2k, out, hstate, cstate,
        t0, cur, (t0==0)?1:0, (t0+cur>=TT)?1:0);
  }
}

// Round 3
// 443.403 us; speedup vs baseline: 5.5287x; 1.1568x over previous
//
#include <hip/hip_runtime.h>

#define TT 512
#define BB 1024

__device__ __forceinline__ float frcp(float x){ return __builtin_amdgcn_rcpf(x); }
__device__ __forceinline__ float fexp2(float x){ return __builtin_amdgcn_exp2f(x); }
__device__ __forceinline__ float fcosr(float x){
  float r = x * 0.15915494309189535f;
  r = r - floorf(r);
  return __builtin_amdgcn_cosf(r);
}

// DPP / swizzle helpers (float through int)
#define DPPZ(v, ctrl) __int_as_float(__builtin_amdgcn_update_dpp(0, __float_as_int(v), (ctrl), 0xF, 0xF, true))
#define DPPR(v, ctrl) __int_as_float(__builtin_amdgcn_update_dpp(__float_as_int(v), __float_as_int(v), (ctrl), 0xF, 0xF, false))
#define SWZ(v, imm)   __int_as_float(__builtin_amdgcn_ds_swizzle(__float_as_int(v), (imm)))

// ---------------- Phase 1: xpre projection (unchanged) ----------------
// xpre[t][b][c], c in [0,40): c<32 -> gate g=c>>3, jj=c&7: x@Wg[:64]+bg+thg
//                 c>=32 -> x@Wi2k + bi2k - bh2k
__global__ __launch_bounds__(256) void qlstm_proj(
    const float* __restrict__ x,
    const float* __restrict__ Wf, const float* __restrict__ bf, const float* __restrict__ thf,
    const float* __restrict__ Wi, const float* __restrict__ bi, const float* __restrict__ thi,
    const float* __restrict__ Wu, const float* __restrict__ bu, const float* __restrict__ thu,
    const float* __restrict__ Wo, const float* __restrict__ bo, const float* __restrict__ tho,
    const float* __restrict__ bh2k,
    const float* __restrict__ Wi2k, const float* __restrict__ bi2k,
    float* __restrict__ buf)
{
  __shared__ float4 wl4[64][10];
  __shared__ float bias[40];
  int tid = threadIdx.x;
  float* wl = (float*)wl4;
  for (int idx = tid; idx < 64*40; idx += 256){
    int d = idx / 40, c = idx - d*40;
    float v;
    if (c < 32){
      int g = c >> 3, jj = c & 7;
      const float* W = (g==0)?Wf:((g==1)?Wi:((g==2)?Wu:Wo));
      v = W[d*8+jj];
    } else {
      v = Wi2k[d*8 + (c-32)];
    }
    wl[d*40+c] = v;
  }
  if (tid < 40){
    int c = tid; float v;
    if (c < 32){
      int g = c >> 3, jj = c & 7;
      const float* bp = (g==0)?bf:((g==1)?bi:((g==2)?bu:bo));
      const float* tp = (g==0)?thf:((g==1)?thi:((g==2)?thu:tho));
      v = bp[jj] + tp[jj];
    } else {
      v = bi2k[c-32] - bh2k[c-32];
    }
    bias[c] = v;
  }
  __syncthreads();

  long r0 = (long)blockIdx.x*512 + tid;
  long r1 = r0 + 256;
  const float4* x0 = (const float4*)(x + r0*64);
  const float4* x1 = (const float4*)(x + r1*64);
  float4 a0[10], a1[10];
#pragma unroll
  for (int q=0;q<10;++q){
    a0[q] = make_float4(bias[q*4+0],bias[q*4+1],bias[q*4+2],bias[q*4+3]);
    a1[q] = a0[q];
  }
#pragma unroll 1
  for (int d4=0; d4<16; ++d4){
    float4 xv0 = x0[d4];
    float4 xv1 = x1[d4];
#pragma unroll
    for (int dd=0; dd<4; ++dd){
      float s0 = (dd==0)?xv0.x:((dd==1)?xv0.y:((dd==2)?xv0.z:xv0.w));
      float s1 = (dd==0)?xv1.x:((dd==1)?xv1.y:((dd==2)?xv1.z:xv1.w));
#pragma unroll
      for (int q=0;q<10;++q){
        float4 wv = wl4[d4*4+dd][q];
        a0[q].x += s0*wv.x; a0[q].y += s0*wv.y; a0[q].z += s0*wv.z; a0[q].w += s0*wv.w;
        a1[q].x += s1*wv.x; a1[q].y += s1*wv.y; a1[q].z += s1*wv.z; a1[q].w += s1*wv.w;
      }
    }
  }
  float4* ob0 = (float4*)(buf + (size_t)r0*40);
  float4* ob1 = (float4*)(buf + (size_t)r1*40);
#pragma unroll
  for (int q=0;q<10;++q){ ob0[q] = a0[q]; ob1[q] = a1[q]; }
}

// ---------------- Phase 2: scan, 32 lanes per batch element ----------------
// lane (e,g,j): e = elem-in-wave (bit5), g = gate (bits 4:3), j = hidden unit (bits 2:0).
// h,c kept valid on ALL lanes. Matvec via DPP row_ror:15 rotation of h against
// per-lane pre-rotated weight columns. Products via quad_perm DPP + xor swizzles.
__global__ __launch_bounds__(256) void qlstm_scan(
    const float* __restrict__ buf,
    const float* __restrict__ Wf, const float* __restrict__ Wi,
    const float* __restrict__ Wu, const float* __restrict__ Wo,
    const float* __restrict__ Wh2k,
    float* __restrict__ out,
    float* __restrict__ hstate, float* __restrict__ cstate,
    int t0, int tc, int initf, int lastf)
{
  int tid = threadIdx.x;
  int j = tid & 7;
  int g = (tid >> 3) & 3;
  int b = blockIdx.x*8 + (tid >> 5);
  bool g0lane = ((tid & 31) < 8);

  // per-lane rotated recurrent weights: step s uses h[(j+s)&7]
  const float* Wg = (g==0)?Wf:((g==1)?Wi:((g==2)?Wu:Wo));
  float wr[8], wkr[8];
#pragma unroll
  for (int s=0;s<8;++s){
    int k = (j + s) & 7;
    wr[s]  = Wg[(64+k)*8 + j];
    wkr[s] = Wh2k[k*8 + j];
  }
  // activation constants: sigmoid for g!=2, tanh for g==2
  float kk = (g==2) ?  2.8853900817779268f : -1.4426950408889634f;
  float aa = (g==2) ? -2.0f : 1.0f;
  float bbc= (g==2) ?  1.0f : 0.0f;

  float h, c;
  if (initf){ h = 0.f; c = 0.f; }
  else { h = hstate[b*8+j]; c = cstate[b*8+j]; }

  const float* bg = buf + (size_t)b*40 + (tid & 31);   // own gate pre (c = g*8+j)
  const float* bk = buf + (size_t)b*40 + 32 + j;       // kernel pre
  const size_t STRIDE = (size_t)BB*40;

  float xgq[4], xkq[4];
#pragma unroll
  for (int i=0;i<4;++i){ xgq[i] = bg[(size_t)i*STRIDE]; xkq[i] = bk[(size_t)i*STRIDE]; }

  for (int tt4 = 0; tt4 < tc; tt4 += 4){
#pragma unroll
    for (int u=0; u<4; ++u){
      int tt = tt4 + u;
      float xg = xgq[u], xk = xkq[u];
      int tn = tt + 4;
      if (tn < tc){
        xgq[u] = bg[(size_t)tn*STRIDE];
        xkq[u] = bk[(size_t)tn*STRIDE];
      }

      // matvec: a = sum_k h[k]*Wg[64+k][j], a4 = sum_k h[k]*Wh2k[k][j]
      float hc = h;
      float a  = hc*wr[0];
      float a4 = hc*wkr[0];
#pragma unroll
      for (int s=1;s<8;++s){
        hc = DPPR(hc, 0x12F);            // row_ror:15 == rotate left by 1
        a  = fmaf(hc, wr[s],  a);
        a4 = fmaf(hc, wkr[s], a4);
      }

      // kernel weight: |prod_j cos(0.5*(kx-ky))| over the 8-lane j-group
      float kv = fcosr(0.5f*(a4 - xk));
      kv *= DPPR(kv, 0xB1);              // quad_perm xor1
      kv *= DPPR(kv, 0x4E);              // quad_perm xor2
      kv *= SWZ(kv, 0x101F);             // xor4
      float wk = fabsf(kv);

      // qlayer for own gate: z = cos(acc + pre)
      float z = fcosr(a + xg);
      // cumprod z[0..j] via row_shr (zero-fill) + masked mul
      float pz = z, s_;
      s_ = DPPZ(pz, 0x111); pz = (j>=1)? pz*s_ : pz;
      s_ = DPPZ(pz, 0x112); pz = (j>=2)? pz*s_ : pz;
      s_ = DPPZ(pz, 0x114); pz = (j>=4)? pz*s_ : pz;
      // prod z[1:]
      float q = (j==0)? 1.0f : z;
      q *= DPPR(q, 0xB1);
      q *= DPPR(q, 0x4E);
      q *= SWZ(q, 0x101F);
      float gq = ((j==0)? q : pz) * wk;

      // activation (uniform code, per-lane constants)
      float e = fexp2(kk*gq);
      float r = frcp(1.0f + e);
      float act = fmaf(aa, r, bbc);

      // cross-gate gather: s_d holds act of lane^(d<<3)
      float s8  = SWZ(act, 0x201F);
      float s16 = SWZ(act, 0x401F);
      float s24 = SWZ(act, 0x601F);
      bool gb1 = (g & 1) != 0, gb2 = (g & 2) != 0;
      float d0 = gb1 ? s8  : act;
      float d1 = gb1 ? s24 : s16;
      float e0 = gb1 ? act : s8;
      float e1 = gb1 ? s16 : s24;
      float fv = gb2 ? d1 : d0;   // sigmoid(f)
      float uv = gb2 ? d0 : d1;   // tanh(u)
      float iv = gb2 ? e1 : e0;   // sigmoid(i)
      float ov = gb2 ? e0 : e1;   // sigmoid(o)

      c = fmaf(fv, c, iv*uv);
      // tanh(c) = 1 - 2/(exp2(2.885*c)+1)
      float e2 = fexp2(2.8853900817779268f*c);
      float r2 = frcp(1.0f + e2);
      float tch = fmaf(-2.0f, r2, 1.0f);
      h = ov * tch;

      if (g0lane) out[((size_t)(t0+tt)*BB + b)*8 + j] = h;
    }
  }

  if (g0lane){
    if (lastf){
      out[(size_t)TT*BB*8 + (size_t)b*8 + j] = h;
      out[(size_t)TT*BB*8 + (size_t)BB*8 + (size_t)b*8 + j] = c;
    } else {
      hstate[b*8+j] = h;
      cstate[b*8+j] = c;
    }
  }
}

extern "C" void kernel_launch(void* const* d_in, const int* in_sizes, int n_in,
                              void* d_out, int out_size, void* d_ws, size_t ws_size,
                              hipStream_t stream)
{
  const float* x    = (const float*)d_in[0];
  const float* Wf   = (const float*)d_in[1];
  const float* bf   = (const float*)d_in[2];
  const float* thf  = (const float*)d_in[3];
  const float* Wi   = (const float*)d_in[4];
  const float* bi   = (const float*)d_in[5];
  const float* thi  = (const float*)d_in[6];
  const float* Wu   = (const float*)d_in[7];
  const float* bu   = (const float*)d_in[8];
  const float* thu  = (const float*)d_in[9];
  const float* Wo   = (const float*)d_in[10];
  const float* bo   = (const float*)d_in[11];
  const float* tho  = (const float*)d_in[12];
  const float* Wh2k = (const float*)d_in[13];
  const float* bh2k = (const float*)d_in[14];
  const float* Wi2k = (const float*)d_in[15];
  const float* bi2k = (const float*)d_in[16];
  float* out = (float*)d_out;

  // ws layout: hstate[8192 f] | cstate[8192 f] | xpre buf [tc][BB][40]
  float* hstate = (float*)d_ws;
  float* cstate = hstate + BB*8;
  float* buf    = cstate + BB*8;
  long long avail = (long long)ws_size - (long long)(2*BB*8*sizeof(float));
  const long long per_step = 40ll*BB*sizeof(float);  // 160 KiB per time step
  int tc = TT;
  while (tc > 4 && (long long)tc*per_step > avail) tc >>= 1;

  for (int t0 = 0; t0 < TT; t0 += tc){
    int cur = (TT - t0 < tc) ? (TT - t0) : tc;
    qlstm_proj<<<(cur*BB)/512, 256, 0, stream>>>(
        x + (size_t)t0*BB*64,
        Wf,bf,thf, Wi,bi,thi, Wu,bu,thu, Wo,bo,tho,
        bh2k, Wi2k, bi2k, buf);
    qlstm_scan<<<BB/8, 256, 0, stream>>>(
        buf, Wf, Wi, Wu, Wo, Wh2k, out, hstate, cstate,
        t0, cur, (t0==0)?1:0, (t0+cur>=TT)?1:0);
  }
}